// Round 3
// baseline (525.249 us; speedup 1.0000x reference)
//
#include <hip/hip_runtime.h>
#include <hip/hip_bf16.h>

// SpectralDense on MI355X.
// out[8192][2048] = (X[8192][2048] @ K[2048][2048]) / sigma1(K)
// sigma1 via: A~ = K^T K / 4 -> 4 squarings -> C = A~^16
//            -> 5 power-iteration matvecs (4 vectors) -> Rayleigh
//            -> sigma = 2 * R^(1/32).
// Chain GEMMs exploit symmetry: only 136 upper-tri 128^2 tiles computed,
// epilogue mirror-writes the transpose tile (same fp-bits). Split-K=4
// (grid (136,4) = 544 blocks ~2.1/CU) -> fp32 partial planes -> reduce4+cast.
// Main GEMM: fp16 MFMA 16x16x32, m97 structure (128^2 tile, BK=64,
// global_load_lds w=16, XOR-swizzled LDS, 2-barrier K-loop), epilogue * (1/sigma).
// Workspace: 88 MiB (P planes aliased by X16 after the chain).

typedef __attribute__((ext_vector_type(8))) _Float16 f16x8;
typedef __attribute__((ext_vector_type(8))) short   s16x8;
typedef __attribute__((ext_vector_type(4))) float   f32x4;

#define DEV __device__ __forceinline__

DEV unsigned short f2bf(float x) {           // round-to-nearest-even fp32->bf16
  unsigned u = __float_as_uint(x);
  unsigned r = (u + 0x7FFFu + ((u >> 16) & 1u)) >> 16;
  return (unsigned short)r;
}
DEV float bf2f(unsigned short b) { return __uint_as_float(((unsigned)b) << 16); }

DEV void gl_lds16(const void* g, void* l) {
  __builtin_amdgcn_global_load_lds((const __attribute__((address_space(1))) void*)g,
                                   (__attribute__((address_space(3))) void*)l,
                                   16, 0, 0);
}

// ---------------------------------------------------------------------------
// GEMM (B^T layout): C[m][n] = scale * sum_{k in my split} A[m][k] * B[n][k]
// A: M x K (2-byte elems), B: N x K (2-byte elems), row stride K elems.
// Split-K across gridDim.y: block (x,y) covers k in [y*ksz, (y+1)*ksz),
// writes fp32 partials to Cg + y*M*N.
// TRI: A==B symmetric product; blockIdx.x indexes the 136 upper-tri tiles,
// epilogue mirror-writes C[cc][rr] = C[rr][cc] (identical fp value).
// LDS tiles [128][64] elems, XOR swizzle byte ^= ((row&7)<<4) applied on BOTH
// the global source (pre-swizzle for global_load_lds's linear write) and the
// ds_read side (rule 21).
// ---------------------------------------------------------------------------
template <bool F16IN, bool TRI>
__global__ __launch_bounds__(256, 2)
void gemm_bt(const char* __restrict__ Ag, const char* __restrict__ Bg,
             float* __restrict__ Cg, int M, int N, int K, int ksz,
             float cscale, const float* __restrict__ scale_ptr)
{
  __shared__ unsigned char smem[32768];     // A: [0,16K), B: [16K,32K)
  const int tid  = threadIdx.x;
  const int lane = tid & 63;
  const int wid  = tid >> 6;

  // XCD-bijective swizzle over blockIdx.x (grid.x is a multiple of 8)
  const int q = (int)gridDim.x >> 3;
  const int wgid = ((int)blockIdx.x & 7) * q + ((int)blockIdx.x >> 3);
  int bm, bn;
  if constexpr (TRI) {
    const int nbm = M >> 7;                 // upper-tri decode, row-major
    int rem = wgid, i = 0;
    while (rem >= nbm - i) { rem -= nbm - i; ++i; }
    bm = i; bn = i + rem;
  } else {
    const int nbm = M >> 7;
    bm = wgid % nbm; bn = wgid / nbm;
  }
  const int m0 = bm << 7, n0 = bn << 7;

  // split-K range and partial-output base
  const int kbeg = (int)blockIdx.y * ksz;
  float* __restrict__ Cmy = Cg + (size_t)blockIdx.y * ((size_t)M * (size_t)N);

  float scale = cscale;
  if (scale_ptr) scale *= scale_ptr[0];

  const f32x4 zero = {0.f, 0.f, 0.f, 0.f};
  f32x4 acc[4][4];
#pragma unroll
  for (int i = 0; i < 4; i++)
#pragma unroll
    for (int j = 0; j < 4; j++) acc[i][j] = zero;

  const int wr = wid >> 1, wc = wid & 1;      // 2x2 wave grid, 64x64 per wave
  const size_t rowstride = (size_t)K * 2;     // bytes

  for (int k0 = kbeg; k0 < kbeg + ksz; k0 += 64) {
    // ---- stage A,B tiles: 16 KB each, 4 passes x (256 thr x 16 B) ----
#pragma unroll
    for (int p = 0; p < 4; p++) {
      const int b   = (p << 12) + (wid << 10) + (lane << 4); // linear tile byte
      const int row = b >> 7;                                 // tile row
      const int scb = (b & 127) ^ ((row & 7) << 4);           // swizzled src col byte
      const size_t goff = (size_t)row * rowstride + (size_t)(k0 << 1) + (size_t)scb;
      gl_lds16(Ag + (size_t)m0 * rowstride + goff, smem + (p << 12) + (wid << 10));
      gl_lds16(Bg + (size_t)n0 * rowstride + goff, smem + 16384 + (p << 12) + (wid << 10));
    }
    __syncthreads();   // compiler drains vmcnt before s_barrier

    // ---- compute: 2 K-slices of 32, 16 MFMA each ----
#pragma unroll
    for (int kk = 0; kk < 2; kk++) {
      s16x8 a[4], b[4];
      const int kb = (kk << 6) + ((lane >> 4) << 4);  // byte offset in 128B row
#pragma unroll
      for (int i = 0; i < 4; i++) {
        const int ar = (wr << 6) + (i << 4) + (lane & 15);
        const int br = (wc << 6) + (i << 4) + (lane & 15);
        a[i] = *(const s16x8*)(smem + ((((ar << 7) + kb)) ^ ((ar & 7) << 4)));
        b[i] = *(const s16x8*)(smem + 16384 + ((((br << 7) + kb)) ^ ((br & 7) << 4)));
      }
#pragma unroll
      for (int i = 0; i < 4; i++)
#pragma unroll
        for (int j = 0; j < 4; j++) {
          if constexpr (F16IN)
            acc[i][j] = __builtin_amdgcn_mfma_f32_16x16x32_f16(
                __builtin_bit_cast(f16x8, a[i]), __builtin_bit_cast(f16x8, b[j]),
                acc[i][j], 0, 0, 0);
          else
            acc[i][j] = __builtin_amdgcn_mfma_f32_16x16x32_bf16(
                a[i], b[j], acc[i][j], 0, 0, 0);
        }
    }
    __syncthreads();
  }

  // ---- epilogue: C/D layout col = lane&15, row = (lane>>4)*4 + reg (m89) ----
  const int ccol = n0 + (wc << 6) + (lane & 15);
  const int crow = m0 + (wr << 6) + ((lane >> 4) << 2);
#pragma unroll
  for (int i = 0; i < 4; i++)
#pragma unroll
    for (int j = 0; j < 4; j++)
#pragma unroll
      for (int r = 0; r < 4; r++) {
        const int rr = crow + (i << 4) + r;
        const int cc = ccol + (j << 4);
        const float v = acc[i][j][r] * scale;
        Cmy[(size_t)rr * (size_t)N + cc] = v;
        if constexpr (TRI) {
          if (bm != bn) Cmy[(size_t)cc * (size_t)N + rr] = v;   // mirror tile
        }
      }
}

// o_bf16[i] = (bf16)(a+b+c+d)  — split-K=4 partial reduce, 8 elems/thread
__global__ __launch_bounds__(256)
void reduce4_bf16(const float* __restrict__ a, const float* __restrict__ b,
                  const float* __restrict__ c, const float* __restrict__ d,
                  unsigned short* __restrict__ o)
{
  const size_t i = (((size_t)blockIdx.x * 256) + threadIdx.x) << 3;
  const f32x4 a0 = *(const f32x4*)(a + i), a1 = *(const f32x4*)(a + i + 4);
  const f32x4 b0 = *(const f32x4*)(b + i), b1 = *(const f32x4*)(b + i + 4);
  const f32x4 c0 = *(const f32x4*)(c + i), c1 = *(const f32x4*)(c + i + 4);
  const f32x4 d0 = *(const f32x4*)(d + i), d1 = *(const f32x4*)(d + i + 4);
  s16x8 r;
#pragma unroll
  for (int e = 0; e < 4; e++) {
    r[e]     = (short)f2bf((a0[e] + b0[e]) + (c0[e] + d0[e]));
    r[e + 4] = (short)f2bf((a1[e] + b1[e]) + (c1[e] + d1[e]));
  }
  *(s16x8*)(o + i) = r;
}

// ---------------------------------------------------------------------------
// y[row][0..3] = sum_c C_bf16[row][c] * v[c][0..3]   (2048 rows, 4 vectors)
// one wave per row; lane covers 32 contiguous cols (64 B coalesced)
// ---------------------------------------------------------------------------
__global__ __launch_bounds__(256)
void matvec4(const unsigned short* __restrict__ Cm,
             const float* __restrict__ vin, float* __restrict__ vout)
{
  const int row  = ((int)blockIdx.x << 2) + ((int)threadIdx.x >> 6);
  const int lane = threadIdx.x & 63;
  const unsigned short* crow = Cm + ((size_t)row << 11) + (lane << 5);
  const float* vp = vin + (lane << 7);
  float s0 = 0.f, s1 = 0.f, s2 = 0.f, s3 = 0.f;
#pragma unroll
  for (int u = 0; u < 4; u++) {
    const s16x8 cv = *(const s16x8*)(crow + (u << 3));
#pragma unroll
    for (int e = 0; e < 8; e++) {
      const float w = bf2f((unsigned short)cv[e]);
      const f32x4 vv = *(const f32x4*)(vp + (((u << 3) + e) << 2));
      s0 += w * vv[0]; s1 += w * vv[1]; s2 += w * vv[2]; s3 += w * vv[3];
    }
  }
#pragma unroll
  for (int d = 32; d > 0; d >>= 1) {
    s0 += __shfl_down(s0, d);
    s1 += __shfl_down(s1, d);
    s2 += __shfl_down(s2, d);
    s3 += __shfl_down(s3, d);
  }
  if (lane == 0) {
    float* o = vout + ((size_t)row << 2);
    o[0] = s0; o[1] = s1; o[2] = s2; o[3] = s3;
  }
}

__global__ void init_v(float* __restrict__ v) {
  const int i = (int)blockIdx.x * 256 + (int)threadIdx.x;  // 8192 values
  unsigned h = (unsigned)i * 2654435761u;
  h ^= h >> 16; h *= 2246822519u; h ^= h >> 13;
  v[i] = (float)(h & 0xFFFFFFu) * (2.0f / 16777216.0f) - 1.0f;
}

// R_j = (vt_j . y_j) / (vt_j . vt_j); sigma = 2 * max_j R_j ^ (1/32); sig[0]=1/sigma
__global__ __launch_bounds__(256)
void rayleigh_k(const float* __restrict__ vt, const float* __restrict__ y,
                float* __restrict__ sig)
{
  __shared__ float part[4][8];
  const int t = threadIdx.x, lane = t & 63, w = t >> 6;
  float num[4] = {0, 0, 0, 0}, den[4] = {0, 0, 0, 0};
  for (int i = t; i < 2048; i += 256) {
    const f32x4 a = *(const f32x4*)(vt + ((size_t)i << 2));
    const f32x4 b = *(const f32x4*)(y + ((size_t)i << 2));
#pragma unroll
    for (int j = 0; j < 4; j++) { num[j] += a[j] * b[j]; den[j] += a[j] * a[j]; }
  }
#pragma unroll
  for (int d = 32; d > 0; d >>= 1)
#pragma unroll
    for (int j = 0; j < 4; j++) {
      num[j] += __shfl_down(num[j], d);
      den[j] += __shfl_down(den[j], d);
    }
  if (lane == 0) {
#pragma unroll
    for (int j = 0; j < 4; j++) { part[w][j] = num[j]; part[w][j + 4] = den[j]; }
  }
  __syncthreads();
  if (t == 0) {
    float R = 0.f;
#pragma unroll
    for (int j = 0; j < 4; j++) {
      const float nj = part[0][j] + part[1][j] + part[2][j] + part[3][j];
      const float dj = part[0][j + 4] + part[1][j + 4] + part[2][j + 4] + part[3][j + 4];
      R = fmaxf(R, nj / dj);
    }
    const float sigma = 2.0f * powf(R, 0.03125f);   // R^(1/32)
    sig[0] = 1.0f / sigma;
  }
}

__global__ __launch_bounds__(256)
void convert_f16(const float* __restrict__ in, _Float16* __restrict__ out) {
  const size_t i = (((size_t)blockIdx.x * 256) + threadIdx.x) << 3;
  const f32x4 a = *(const f32x4*)(in + i);
  const f32x4 b = *(const f32x4*)(in + i + 4);
  f16x8 o;
#pragma unroll
  for (int e = 0; e < 4; e++) { o[e] = (_Float16)a[e]; o[e + 4] = (_Float16)b[e]; }
  *(f16x8*)(out + i) = o;
}

// KT[f][d] = (f16) K[d][f], 64x64 tiles via LDS (stride 65: conflict-free)
__global__ __launch_bounds__(256)
void transpose_f16(const float* __restrict__ Kin, _Float16* __restrict__ KT) {
  __shared__ float tile[64][65];
  const int t = threadIdx.x;
  const int c = t & 63, rq = t >> 6;
  const int d0 = (int)blockIdx.x << 6, f0 = (int)blockIdx.y << 6;
#pragma unroll
  for (int p = 0; p < 16; p++) {
    const int rr = (p << 2) + rq;
    tile[rr][c] = Kin[(size_t)(d0 + rr) * 2048 + f0 + c];
  }
  __syncthreads();
#pragma unroll
  for (int p = 0; p < 16; p++) {
    const int fl = (p << 2) + rq;
    KT[(size_t)(f0 + fl) * 2048 + d0 + c] = (_Float16)tile[c][fl];
  }
}

// ---------------------------------------------------------------------------
extern "C" void kernel_launch(void* const* d_in, const int* in_sizes, int n_in,
                              void* d_out, int out_size, void* d_ws, size_t ws_size,
                              hipStream_t stream)
{
  (void)in_sizes; (void)n_in; (void)out_size; (void)ws_size;
  const float* X  = (const float*)d_in[0];   // [8192][2048] fp32
  const float* Km = (const float*)d_in[1];   // [2048][2048] fp32
  float* out = (float*)d_out;                // [8192][2048] fp32
  char* ws = (char*)d_ws;

  // Workspace layout (88 MiB total; P aliased by X16 after the chain):
  _Float16* KT  = (_Float16*)ws;                              // [0,8M)
  unsigned short* buf0 = (unsigned short*)(ws + (8u << 20));  // [8M,16M)
  unsigned short* buf1 = (unsigned short*)(ws + (16u << 20)); // [16M,24M)
  float* P   = (float*)(ws + (24u << 20));                    // [24M,88M): 4 fp32 planes
  _Float16* X16 = (_Float16*)(ws + (24u << 20));              // [24M,56M): reuses P
  float* V0  = (float*)(ws + (56u << 20));                    // reuses P plane 2
  float* V1  = V0 + 8192;
  float* sig = V1 + 8192;

  const size_t PN = (size_t)2048 * 2048;     // partial plane elems

  transpose_f16<<<dim3(32, 32), 256, 0, stream>>>(Km, KT);

  // A~ = (K^T K)/4 : symmetric -> 136 upper tiles, split-K=4
  gemm_bt<true, true><<<dim3(136, 4), 256, 0, stream>>>(
      (const char*)KT, (const char*)KT, P, 2048, 2048, 2048, 512, 0.25f, nullptr);
  reduce4_bf16<<<2048, 256, 0, stream>>>(P, P + PN, P + 2 * PN, P + 3 * PN, buf0);

  // 4 squarings: A~^2, A~^4, A~^8, A~^16 (all symmetric)
  unsigned short* src = buf0;
  unsigned short* dst = buf1;
  for (int s = 0; s < 4; s++) {
    gemm_bt<false, true><<<dim3(136, 4), 256, 0, stream>>>(
        (const char*)src, (const char*)src, P, 2048, 2048, 2048, 512, 1.0f, nullptr);
    reduce4_bf16<<<2048, 256, 0, stream>>>(P, P + PN, P + 2 * PN, P + 3 * PN, dst);
    unsigned short* t = src; src = dst; dst = t;
  }
  // C = A~^16 now in `src` (buf0)

  // X -> f16 (after the chain: X16 aliases P planes 0-1)
  convert_f16<<<8192, 256, 0, stream>>>(X, X16);

  // power iteration on C, 4 vectors, 5 multiplies
  init_v<<<32, 256, 0, stream>>>(V0);
  const int T = 5;
  for (int it = 0; it < T; it++)
    matvec4<<<512, 256, 0, stream>>>(src, (it & 1) ? V1 : V0, (it & 1) ? V0 : V1);
  const float* vt = ((T - 1) & 1) ? V1 : V0;   // input of last multiply
  const float* yv = ((T - 1) & 1) ? V0 : V1;   // output of last multiply
  rayleigh_k<<<1, 256, 0, stream>>>(vt, yv, sig);

  // out = X @ K / sigma : out[m][f] = sig * sum_d X16[m][d]*KT[f][d]
  gemm_bt<true, false><<<dim3(1024, 1), 256, 0, stream>>>(
      (const char*)X16, (const char*)KT, out, 8192, 2048, 2048, 2048, 1.0f, sig);
}

// Round 4
// 417.810 us; speedup vs baseline: 1.2571x; 1.2571x over previous
//
#include <hip/hip_runtime.h>
#include <hip/hip_bf16.h>

// SpectralDense on MI355X.
// out[8192][2048] = (X[8192][2048] @ K[2048][2048]) / sigma1(K)
// sigma1 via: A~ = K^T K / 4 -> 4 squarings -> C = A~^16
//            -> 5 power-iteration matvecs (4 vectors) -> Rayleigh
//            -> sigma = 2 * R^(1/32).
// Chain GEMMs exploit symmetry: only 136 upper-tri 128^2 tiles computed,
// written COALESCED to compact per-tile fp32 partial planes (split-K=4,
// grid (136,4) ~2.1 blocks/CU). reduce_sym sums the 4 planes, casts bf16,
// and writes BOTH the upper tile and its mirror (via LDS transpose) with
// fully coalesced stores. (r3 lesson: mirror in the GEMM epilogue was a
// 64-line scatter per store -> +60 us; mirror belongs in the reducer.)
// Main GEMM: fp16 MFMA 16x16x32, m97 structure (128^2 tile, BK=64,
// global_load_lds w=16, XOR-swizzled LDS, 2-barrier K-loop), epilogue * (1/sigma).
// Workspace: 58 MiB live (X16 aliases the dead partial planes afterwards).

typedef __attribute__((ext_vector_type(8))) _Float16 f16x8;
typedef __attribute__((ext_vector_type(8))) short   s16x8;
typedef __attribute__((ext_vector_type(4))) short   s16x4;
typedef __attribute__((ext_vector_type(4))) float   f32x4;

#define DEV __device__ __forceinline__

DEV unsigned short f2bf(float x) {           // round-to-nearest-even fp32->bf16
  unsigned u = __float_as_uint(x);
  unsigned r = (u + 0x7FFFu + ((u >> 16) & 1u)) >> 16;
  return (unsigned short)r;
}
DEV float bf2f(unsigned short b) { return __uint_as_float(((unsigned)b) << 16); }

DEV void gl_lds16(const void* g, void* l) {
  __builtin_amdgcn_global_load_lds((const __attribute__((address_space(1))) void*)g,
                                   (__attribute__((address_space(3))) void*)l,
                                   16, 0, 0);
}

// ---------------------------------------------------------------------------
// GEMM (B^T layout): C[m][n] = scale * sum_{k in my split} A[m][k] * B[n][k]
// A: M x K (2-byte elems), B: N x K (2-byte elems), row stride K elems.
// Split-K across gridDim.y: block (x,y) covers k in [y*ksz, (y+1)*ksz).
// TRI: A==B symmetric; blockIdx.x indexes 136 upper-tri tiles; the block
// writes ONLY its own tile, compactly: plane stride = gridDim.x*16384 fp32,
// tile base = wgid*16384, row-major 128x128 (coalesced 64B runs).
// non-TRI: full row-major M x N fp32 (or bf16 never used here) output.
// LDS tiles [128][64] elems, XOR swizzle byte ^= ((row&7)<<4) applied on BOTH
// the global source (pre-swizzle for global_load_lds's linear write) and the
// ds_read side (rule 21).
// ---------------------------------------------------------------------------
template <bool F16IN, bool TRI>
__global__ __launch_bounds__(256, 2)
void gemm_bt(const char* __restrict__ Ag, const char* __restrict__ Bg,
             float* __restrict__ Cg, int M, int N, int K, int ksz,
             float cscale, const float* __restrict__ scale_ptr)
{
  __shared__ unsigned char smem[32768];     // A: [0,16K), B: [16K,32K)
  const int tid  = threadIdx.x;
  const int lane = tid & 63;
  const int wid  = tid >> 6;

  // XCD-bijective swizzle over blockIdx.x (grid.x is a multiple of 8)
  const int q = (int)gridDim.x >> 3;
  const int wgid = ((int)blockIdx.x & 7) * q + ((int)blockIdx.x >> 3);
  int bm, bn;
  if constexpr (TRI) {
    const int nbm = M >> 7;                 // upper-tri decode, row-major
    int rem = wgid, i = 0;
    while (rem >= nbm - i) { rem -= nbm - i; ++i; }
    bm = i; bn = i + rem;
  } else {
    const int nbm = M >> 7;
    bm = wgid % nbm; bn = wgid / nbm;
  }
  const int m0 = bm << 7, n0 = bn << 7;

  // split-K range and partial-output base
  const int kbeg = (int)blockIdx.y * ksz;
  const size_t plane = TRI ? ((size_t)gridDim.x << 14) : ((size_t)M * (size_t)N);
  float* __restrict__ Cmy = Cg + (size_t)blockIdx.y * plane;

  float scale = cscale;
  if (scale_ptr) scale *= scale_ptr[0];

  const f32x4 zero = {0.f, 0.f, 0.f, 0.f};
  f32x4 acc[4][4];
#pragma unroll
  for (int i = 0; i < 4; i++)
#pragma unroll
    for (int j = 0; j < 4; j++) acc[i][j] = zero;

  const int wr = wid >> 1, wc = wid & 1;      // 2x2 wave grid, 64x64 per wave
  const size_t rowstride = (size_t)K * 2;     // bytes

  for (int k0 = kbeg; k0 < kbeg + ksz; k0 += 64) {
    // ---- stage A,B tiles: 16 KB each, 4 passes x (256 thr x 16 B) ----
#pragma unroll
    for (int p = 0; p < 4; p++) {
      const int b   = (p << 12) + (wid << 10) + (lane << 4); // linear tile byte
      const int row = b >> 7;                                 // tile row
      const int scb = (b & 127) ^ ((row & 7) << 4);           // swizzled src col byte
      const size_t goff = (size_t)row * rowstride + (size_t)(k0 << 1) + (size_t)scb;
      gl_lds16(Ag + (size_t)m0 * rowstride + goff, smem + (p << 12) + (wid << 10));
      gl_lds16(Bg + (size_t)n0 * rowstride + goff, smem + 16384 + (p << 12) + (wid << 10));
    }
    __syncthreads();   // compiler drains vmcnt before s_barrier

    // ---- compute: 2 K-slices of 32, 16 MFMA each ----
#pragma unroll
    for (int kk = 0; kk < 2; kk++) {
      s16x8 a[4], b[4];
      const int kb = (kk << 6) + ((lane >> 4) << 4);  // byte offset in 128B row
#pragma unroll
      for (int i = 0; i < 4; i++) {
        const int ar = (wr << 6) + (i << 4) + (lane & 15);
        const int br = (wc << 6) + (i << 4) + (lane & 15);
        a[i] = *(const s16x8*)(smem + ((((ar << 7) + kb)) ^ ((ar & 7) << 4)));
        b[i] = *(const s16x8*)(smem + 16384 + ((((br << 7) + kb)) ^ ((br & 7) << 4)));
      }
#pragma unroll
      for (int i = 0; i < 4; i++)
#pragma unroll
        for (int j = 0; j < 4; j++) {
          if constexpr (F16IN)
            acc[i][j] = __builtin_amdgcn_mfma_f32_16x16x32_f16(
                __builtin_bit_cast(f16x8, a[i]), __builtin_bit_cast(f16x8, b[j]),
                acc[i][j], 0, 0, 0);
          else
            acc[i][j] = __builtin_amdgcn_mfma_f32_16x16x32_bf16(
                a[i], b[j], acc[i][j], 0, 0, 0);
        }
    }
    __syncthreads();
  }

  // ---- epilogue: C/D layout col = lane&15, row = (lane>>4)*4 + reg (m89) ----
  const int lcol = (wc << 6) + (lane & 15);
  const int lrow = (wr << 6) + ((lane >> 4) << 2);
#pragma unroll
  for (int i = 0; i < 4; i++)
#pragma unroll
    for (int j = 0; j < 4; j++)
#pragma unroll
      for (int r = 0; r < 4; r++) {
        const int rr = lrow + (i << 4) + r;
        const int cc = lcol + (j << 4);
        const float v = acc[i][j][r] * scale;
        if constexpr (TRI)
          Cmy[((size_t)wgid << 14) + (rr << 7) + cc] = v;     // compact tile
        else
          Cmy[(size_t)(m0 + rr) * (size_t)N + (n0 + cc)] = v;
      }
}

// ---------------------------------------------------------------------------
// reduce_sym: per upper-tri tile b (grid=136), sum 4 compact fp32 partial
// planes -> bf16; write upper tile coalesced; write mirror tile (bm!=bn)
// via LDS transpose with coalesced 32B row-runs.
// ---------------------------------------------------------------------------
__global__ __launch_bounds__(256, 2)
void reduce_sym(const float* __restrict__ P, unsigned short* __restrict__ o)
{
  __shared__ unsigned short tl[128][136];     // transposed tile, 16B-aligned rows
  const int b = (int)blockIdx.x;              // 0..135 upper-tri tile id
  int rem = b, i = 0;
  while (rem >= 16 - i) { rem -= 16 - i; ++i; }
  const int bm = i, bn = i + rem;
  const int t = threadIdx.x;
  const size_t PS = (size_t)136 << 14;        // plane stride (elems)
  const float* p = P + ((size_t)b << 14);

  // phase 1: sum planes, write upper tile (8B/lane, contiguous), stash
  // transposed copy in LDS (tl[c][r] = tile[r][c])
#pragma unroll
  for (int s = 0; s < 16; s++) {
    const int idx = (s << 10) + (t << 2);     // 4 consecutive elems
    const int r = idx >> 7, c = idx & 127;
    f32x4 v = *(const f32x4*)(p + idx);
    v += *(const f32x4*)(p + PS + idx);
    v += *(const f32x4*)(p + 2 * PS + idx);
    v += *(const f32x4*)(p + 3 * PS + idx);
    s16x4 u;
#pragma unroll
    for (int e = 0; e < 4; e++) u[e] = (short)f2bf(v[e]);
    *(s16x4*)(o + (((size_t)(bm << 7) + r) << 11) + (bn << 7) + c) = u;
#pragma unroll
    for (int e = 0; e < 4; e++) tl[c + e][r] = (unsigned short)u[e];
  }
  __syncthreads();
  if (bm == bn) return;                       // diagonal: no mirror needed

  // phase 2: mirror tile; lanes 0..7 of each group share an out row ->
  // 128B contiguous runs per 8 lanes
#pragma unroll
  for (int pass = 0; pass < 4; pass++) {
    const int crw = (pass << 5) + (t >> 3);   // out row (= tile col)
    const int r0  = (t & 7) << 4;             // out col base (= tile row)
    const s16x8 w0 = *(const s16x8*)(&tl[crw][r0]);
    const s16x8 w1 = *(const s16x8*)(&tl[crw][r0 + 8]);
    unsigned short* od = o + (((size_t)(bn << 7) + crw) << 11) + (bm << 7) + r0;
    *(s16x8*)(od)     = w0;
    *(s16x8*)(od + 8) = w1;
  }
}

// ---------------------------------------------------------------------------
// y[row][0..3] = sum_c C_bf16[row][c] * v[c][0..3]   (2048 rows, 4 vectors)
// one wave per row; lane covers 32 contiguous cols (64 B coalesced)
// ---------------------------------------------------------------------------
__global__ __launch_bounds__(256)
void matvec4(const unsigned short* __restrict__ Cm,
             const float* __restrict__ vin, float* __restrict__ vout)
{
  const int row  = ((int)blockIdx.x << 2) + ((int)threadIdx.x >> 6);
  const int lane = threadIdx.x & 63;
  const unsigned short* crow = Cm + ((size_t)row << 11) + (lane << 5);
  const float* vp = vin + (lane << 7);
  float s0 = 0.f, s1 = 0.f, s2 = 0.f, s3 = 0.f;
#pragma unroll
  for (int u = 0; u < 4; u++) {
    const s16x8 cv = *(const s16x8*)(crow + (u << 3));
#pragma unroll
    for (int e = 0; e < 8; e++) {
      const float w = bf2f((unsigned short)cv[e]);
      const f32x4 vv = *(const f32x4*)(vp + (((u << 3) + e) << 2));
      s0 += w * vv[0]; s1 += w * vv[1]; s2 += w * vv[2]; s3 += w * vv[3];
    }
  }
#pragma unroll
  for (int d = 32; d > 0; d >>= 1) {
    s0 += __shfl_down(s0, d);
    s1 += __shfl_down(s1, d);
    s2 += __shfl_down(s2, d);
    s3 += __shfl_down(s3, d);
  }
  if (lane == 0) {
    float* o = vout + ((size_t)row << 2);
    o[0] = s0; o[1] = s1; o[2] = s2; o[3] = s3;
  }
}

__global__ void init_v(float* __restrict__ v) {
  const int i = (int)blockIdx.x * 256 + (int)threadIdx.x;  // 8192 values
  unsigned h = (unsigned)i * 2654435761u;
  h ^= h >> 16; h *= 2246822519u; h ^= h >> 13;
  v[i] = (float)(h & 0xFFFFFFu) * (2.0f / 16777216.0f) - 1.0f;
}

// R_j = (vt_j . y_j) / (vt_j . vt_j); sigma = 2 * max_j R_j ^ (1/32); sig[0]=1/sigma
__global__ __launch_bounds__(256)
void rayleigh_k(const float* __restrict__ vt, const float* __restrict__ y,
                float* __restrict__ sig)
{
  __shared__ float part[4][8];
  const int t = threadIdx.x, lane = t & 63, w = t >> 6;
  float num[4] = {0, 0, 0, 0}, den[4] = {0, 0, 0, 0};
  for (int i = t; i < 2048; i += 256) {
    const f32x4 a = *(const f32x4*)(vt + ((size_t)i << 2));
    const f32x4 b = *(const f32x4*)(y + ((size_t)i << 2));
#pragma unroll
    for (int j = 0; j < 4; j++) { num[j] += a[j] * b[j]; den[j] += a[j] * a[j]; }
  }
#pragma unroll
  for (int d = 32; d > 0; d >>= 1)
#pragma unroll
    for (int j = 0; j < 4; j++) {
      num[j] += __shfl_down(num[j], d);
      den[j] += __shfl_down(den[j], d);
    }
  if (lane == 0) {
#pragma unroll
    for (int j = 0; j < 4; j++) { part[w][j] = num[j]; part[w][j + 4] = den[j]; }
  }
  __syncthreads();
  if (t == 0) {
    float R = 0.f;
#pragma unroll
    for (int j = 0; j < 4; j++) {
      const float nj = part[0][j] + part[1][j] + part[2][j] + part[3][j];
      const float dj = part[0][j + 4] + part[1][j + 4] + part[2][j + 4] + part[3][j + 4];
      R = fmaxf(R, nj / dj);
    }
    const float sigma = 2.0f * powf(R, 0.03125f);   // R^(1/32)
    sig[0] = 1.0f / sigma;
  }
}

__global__ __launch_bounds__(256)
void convert_f16(const float* __restrict__ in, _Float16* __restrict__ out) {
  const size_t i = (((size_t)blockIdx.x * 256) + threadIdx.x) << 3;
  const f32x4 a = *(const f32x4*)(in + i);
  const f32x4 b = *(const f32x4*)(in + i + 4);
  f16x8 o;
#pragma unroll
  for (int e = 0; e < 4; e++) { o[e] = (_Float16)a[e]; o[e + 4] = (_Float16)b[e]; }
  *(f16x8*)(out + i) = o;
}

// KT[f][d] = (f16) K[d][f], 64x64 tiles via LDS (stride 65: conflict-free)
__global__ __launch_bounds__(256)
void transpose_f16(const float* __restrict__ Kin, _Float16* __restrict__ KT) {
  __shared__ float tile[64][65];
  const int t = threadIdx.x;
  const int c = t & 63, rq = t >> 6;
  const int d0 = (int)blockIdx.x << 6, f0 = (int)blockIdx.y << 6;
#pragma unroll
  for (int p = 0; p < 16; p++) {
    const int rr = (p << 2) + rq;
    tile[rr][c] = Kin[(size_t)(d0 + rr) * 2048 + f0 + c];
  }
  __syncthreads();
#pragma unroll
  for (int p = 0; p < 16; p++) {
    const int fl = (p << 2) + rq;
    KT[(size_t)(f0 + fl) * 2048 + d0 + c] = (_Float16)tile[c][fl];
  }
}

// ---------------------------------------------------------------------------
extern "C" void kernel_launch(void* const* d_in, const int* in_sizes, int n_in,
                              void* d_out, int out_size, void* d_ws, size_t ws_size,
                              hipStream_t stream)
{
  (void)in_sizes; (void)n_in; (void)out_size; (void)ws_size;
  const float* X  = (const float*)d_in[0];   // [8192][2048] fp32
  const float* Km = (const float*)d_in[1];   // [2048][2048] fp32
  float* out = (float*)d_out;                // [8192][2048] fp32
  char* ws = (char*)d_ws;

  // Workspace layout (58 MiB live; X16 aliases P after the chain):
  _Float16* KT  = (_Float16*)ws;                              // [0,8M)
  unsigned short* buf0 = (unsigned short*)(ws + (8u << 20));  // [8M,16M)
  unsigned short* buf1 = (unsigned short*)(ws + (16u << 20)); // [16M,24M)
  float* P   = (float*)(ws + (24u << 20));                    // 4 compact planes, 34M
  _Float16* X16 = (_Float16*)(ws + (24u << 20));              // [24M,56M): reuses P
  float* V0  = (float*)(ws + (58u << 20));                    // vectors + sigma
  float* V1  = V0 + 8192;
  float* sig = V1 + 8192;

  transpose_f16<<<dim3(32, 32), 256, 0, stream>>>(Km, KT);

  // A~ = (K^T K)/4 : symmetric -> 136 upper tiles, split-K=4, compact partials
  gemm_bt<true, true><<<dim3(136, 4), 256, 0, stream>>>(
      (const char*)KT, (const char*)KT, P, 2048, 2048, 2048, 512, 0.25f, nullptr);
  reduce_sym<<<136, 256, 0, stream>>>(P, buf0);

  // 4 squarings: A~^2, A~^4, A~^8, A~^16 (all symmetric)
  unsigned short* src = buf0;
  unsigned short* dst = buf1;
  for (int s = 0; s < 4; s++) {
    gemm_bt<false, true><<<dim3(136, 4), 256, 0, stream>>>(
        (const char*)src, (const char*)src, P, 2048, 2048, 2048, 512, 1.0f, nullptr);
    reduce_sym<<<136, 256, 0, stream>>>(P, dst);
    unsigned short* t = src; src = dst; dst = t;
  }
  // C = A~^16 now in `src` (buf0)

  // X -> f16 (after the chain: X16 aliases the dead P planes)
  convert_f16<<<8192, 256, 0, stream>>>(X, X16);

  // power iteration on C, 4 vectors, 5 multiplies
  init_v<<<32, 256, 0, stream>>>(V0);
  const int T = 5;
  for (int it = 0; it < T; it++)
    matvec4<<<512, 256, 0, stream>>>(src, (it & 1) ? V1 : V0, (it & 1) ? V0 : V1);
  const float* vt = ((T - 1) & 1) ? V1 : V0;   // input of last multiply
  const float* yv = ((T - 1) & 1) ? V0 : V1;   // output of last multiply
  rayleigh_k<<<1, 256, 0, stream>>>(vt, yv, sig);

  // out = X @ K / sigma : out[m][f] = sig * sum_d X16[m][d]*KT[f][d]
  gemm_bt<true, false><<<dim3(1024, 1), 256, 0, stream>>>(
      (const char*)X16, (const char*)KT, out, 8192, 2048, 2048, 2048, 1.0f, sig);
}

// Round 6
// 391.931 us; speedup vs baseline: 1.3402x; 1.0660x over previous
//
#include <hip/hip_runtime.h>
#include <hip/hip_bf16.h>

// SpectralDense on MI355X.
// out[8192][2048] = (X[8192][2048] @ K[2048][2048]) / sigma1(K)
// sigma1: A~ = K^T K / 4 -> 4 squarings -> C = A~^16 -> 5 power-iteration
// matvecs (4 vectors) -> Rayleigh -> sigma = 2 * R^(1/32).
//
// gemm256: 256^2 tile, BK=64, 512 thr / 8 waves (2Mx4N), 128 KiB LDS dbuf,
// 4 phases/K-tile with counted vmcnt (T3+T4+T5).
// r5 post-mortem: wave (wm,wn) reads B pass wn every phase and A passes
// {wm*2, wm*2+1} (64-row blocks of its 128-row half) at phases {0/1, 2/3}.
// Correct issue order per tile: B0,B1 | B2,B3 | A(0-63),A(128-191) |
// A(64-127),A(192-255); waits: end-ph1 vmcnt(4) covers ph2/3 reads,
// end-ph3 vmcnt(2) covers next tile's ph0/1 reads. Proven by queue count:
// steady-state outstanding at ph1-end = 2 late-A(cur)+4 B(next) -> oldest2;
// at ph3-end = 8(next) -> oldest6 = B-all + early-A. Never vmcnt(0) in-loop.
// LDS XOR swizzle byte^=((row&7)<<4) on BOTH global source (pre-swizzle for
// global_load_lds linear write) and ds_read (rule 21); conflict-free (r1-r4).
//
// Chain GEMMs: symmetric -> 36 upper-tri 256^2 tiles, split-K=4 (grid 36x4),
// quadrant epilogue into compact 136-tile fp32 partial planes; reduce_sym
// (proven r4) sums 4 planes, casts bf16, mirror-writes via LDS transpose.
// Workspace: 58 MiB live (X16 aliases dead partial planes).

typedef __attribute__((ext_vector_type(8))) _Float16 f16x8;
typedef __attribute__((ext_vector_type(8))) short   s16x8;
typedef __attribute__((ext_vector_type(4))) short   s16x4;
typedef __attribute__((ext_vector_type(4))) float   f32x4;

#define DEV __device__ __forceinline__
#define FENCE() asm volatile("" ::: "memory")
#define BAR()   __builtin_amdgcn_s_barrier()

DEV unsigned short f2bf(float x) {           // round-to-nearest-even fp32->bf16
  unsigned u = __float_as_uint(x);
  unsigned r = (u + 0x7FFFu + ((u >> 16) & 1u)) >> 16;
  return (unsigned short)r;
}
DEV float bf2f(unsigned short b) { return __uint_as_float(((unsigned)b) << 16); }

DEV void gl_lds16(const void* g, void* l) {
  __builtin_amdgcn_global_load_lds((const __attribute__((address_space(1))) void*)g,
                                   (__attribute__((address_space(3))) void*)l,
                                   16, 0, 0);
}

// one staging pass: 512 thr x 16 B = 8 KB. P<4: B rows P*64..+63; P>=4:
// A rows (P-4)*64..+63. LDS dest linear (global_load_lds requirement);
// global source column pre-swizzled so LDS lands XOR-swizzled.
template <int P>
DEV void stage1(const char* Ag, const char* Bg, unsigned char* smem,
                int tid, size_t rowstride, int m0, int n0, int kt, int buf)
{
  const int lb   = tid << 4;          // 0..8191
  const int rip  = lb >> 7;           // row in pass (0..63)
  const int colb = lb & 127;
  const int scb  = colb ^ ((rip & 7) << 4);
  if constexpr (P < 4) {
    const int grow = (P << 6) + rip;
    gl_lds16(Bg + (size_t)(n0 + grow) * rowstride + (size_t)kt * 2 + scb,
             smem + (buf << 16) + 32768 + (P << 13) + lb);
  } else {
    const int grow = ((P - 4) << 6) + rip;
    gl_lds16(Ag + (size_t)(m0 + grow) * rowstride + (size_t)kt * 2 + scb,
             smem + (buf << 16) + ((P - 4) << 13) + lb);
  }
}

// ---------------------------------------------------------------------------
// gemm256: C[m][n] = scale * sum_{k in split} A[m][k] * B[n][k]  (B^T layout)
// A: M x K, B: N x K (2-byte elems). 256^2 tile, BK=64, 512 threads.
// TRI: A==B symmetric, blockIdx.x in [0,36) upper-tri 256-tiles, quadrant
// epilogue into compact 136 x 128^2 fp32 planes (plane stride 136*16384).
// non-TRI: full row-major fp32 output with scale (and *scale_ptr if given).
// ---------------------------------------------------------------------------
template <bool F16IN, bool TRI>
__global__ __launch_bounds__(512, 2)
void gemm256(const char* __restrict__ Ag, const char* __restrict__ Bg,
             float* __restrict__ Cg, int M, int N, int K, int ksz,
             float cscale, const float* __restrict__ scale_ptr)
{
  __shared__ unsigned char smem[131072];    // 2 bufs x (A 32K + B 32K)
  const int tid  = threadIdx.x;
  const int lane = tid & 63;
  const int wid  = tid >> 6;                // 8 waves: wm=wid>>2, wn=wid&3

  int bm, bn;
  if constexpr (TRI) {
    int rem = (int)blockIdx.x, i = 0;       // upper-tri decode over 8x8
    while (rem >= 8 - i) { rem -= 8 - i; ++i; }
    bm = i; bn = i + rem;
  } else {
    const int q = (int)gridDim.x >> 3;      // XCD-bijective swizzle
    const int wgid = ((int)blockIdx.x & 7) * q + ((int)blockIdx.x >> 3);
    const int nbm = M >> 8;
    bm = wgid % nbm; bn = wgid / nbm;
  }
  const int m0 = bm << 8, n0 = bn << 8;

  const int kbeg = (int)blockIdx.y * ksz;
  const int NT   = ksz >> 6;
  float* __restrict__ Cmy =
      Cg + (size_t)blockIdx.y * (TRI ? ((size_t)136 << 14) : ((size_t)M * (size_t)N));

  float scale = cscale;
  if (scale_ptr) scale *= scale_ptr[0];

  const size_t rowstride = (size_t)K * 2;   // bytes

  const f32x4 zero = {0.f, 0.f, 0.f, 0.f};
  f32x4 acc[8][4];
#pragma unroll
  for (int i = 0; i < 8; i++)
#pragma unroll
    for (int j = 0; j < 4; j++) acc[i][j] = zero;

  // frag readers (both-sides swizzle)
  auto rdA = [&](int cur, int i, int kk) -> s16x8 {
    const int row = ((wid >> 2) << 7) + (i << 4) + (lane & 15);
    const int kb  = (kk << 6) + ((lane >> 4) << 4);
    return *(const s16x8*)(smem + (cur << 16) + (row << 7) + (kb ^ ((row & 7) << 4)));
  };
  auto rdB = [&](int cur, int j, int kk) -> s16x8 {
    const int row = ((wid & 3) << 6) + (j << 4) + (lane & 15);
    const int kb  = (kk << 6) + ((lane >> 4) << 4);
    return *(const s16x8*)(smem + (cur << 16) + 32768 + (row << 7) + (kb ^ ((row & 7) << 4)));
  };
  auto MM = [&](const s16x8& a, const s16x8& b, f32x4 c) -> f32x4 {
    if constexpr (F16IN)
      return __builtin_amdgcn_mfma_f32_16x16x32_f16(
          __builtin_bit_cast(f16x8, a), __builtin_bit_cast(f16x8, b), c, 0, 0, 0);
    else
      return __builtin_amdgcn_mfma_f32_16x16x32_bf16(a, b, c, 0, 0, 0);
  };

  // ---- prologue: stage tile 0, issue order B0..B3, A(0-63), A(128-191),
  //      A(64-127), A(192-255); wait oldest-6 (= everything ph0/ph1 read) ----
  stage1<0>(Ag, Bg, smem, tid, rowstride, m0, n0, kbeg, 0);
  stage1<1>(Ag, Bg, smem, tid, rowstride, m0, n0, kbeg, 0);
  stage1<2>(Ag, Bg, smem, tid, rowstride, m0, n0, kbeg, 0);
  stage1<3>(Ag, Bg, smem, tid, rowstride, m0, n0, kbeg, 0);
  stage1<4>(Ag, Bg, smem, tid, rowstride, m0, n0, kbeg, 0);
  stage1<6>(Ag, Bg, smem, tid, rowstride, m0, n0, kbeg, 0);
  stage1<5>(Ag, Bg, smem, tid, rowstride, m0, n0, kbeg, 0);
  stage1<7>(Ag, Bg, smem, tid, rowstride, m0, n0, kbeg, 0);
  asm volatile("s_waitcnt vmcnt(2)" ::: "memory");
  BAR(); FENCE();

  int cur = 0;
  for (int t = 0; t < NT; ++t) {
    const int nxt = cur ^ 1;
    const int kn  = (t + 1 < NT) ? kbeg + ((t + 1) << 6) : kbeg;  // clamp tail
    s16x8 aq[4][2], bq[2][2];

    // ---- ph0: quad (i 0..3, j 0..1); stage B0,B1 of t+1 ----
#pragma unroll
    for (int i = 0; i < 4; i++)
#pragma unroll
      for (int kk = 0; kk < 2; kk++) aq[i][kk] = rdA(cur, i, kk);
#pragma unroll
    for (int j = 0; j < 2; j++)
#pragma unroll
      for (int kk = 0; kk < 2; kk++) bq[j][kk] = rdB(cur, j, kk);
    stage1<0>(Ag, Bg, smem, tid, rowstride, m0, n0, kn, nxt);
    stage1<1>(Ag, Bg, smem, tid, rowstride, m0, n0, kn, nxt);
    FENCE(); BAR();
    __builtin_amdgcn_s_setprio(1);
#pragma unroll
    for (int i = 0; i < 4; i++)
#pragma unroll
      for (int j = 0; j < 2; j++)
#pragma unroll
        for (int kk = 0; kk < 2; kk++)
          acc[i][j] = MM(aq[i][kk], bq[j][kk], acc[i][j]);
    __builtin_amdgcn_s_setprio(0);
    FENCE(); BAR();

    // ---- ph1: quad (i 0..3, j 2..3) reuse aq; stage B2,B3;
    //      end-of-phase vmcnt(4): late-A of cur landed (ph2/ph3 reads) ----
#pragma unroll
    for (int j = 0; j < 2; j++)
#pragma unroll
      for (int kk = 0; kk < 2; kk++) bq[j][kk] = rdB(cur, j + 2, kk);
    stage1<2>(Ag, Bg, smem, tid, rowstride, m0, n0, kn, nxt);
    stage1<3>(Ag, Bg, smem, tid, rowstride, m0, n0, kn, nxt);
    FENCE(); BAR();
    __builtin_amdgcn_s_setprio(1);
#pragma unroll
    for (int i = 0; i < 4; i++)
#pragma unroll
      for (int j = 0; j < 2; j++)
#pragma unroll
        for (int kk = 0; kk < 2; kk++)
          acc[i][j + 2] = MM(aq[i][kk], bq[j][kk], acc[i][j + 2]);
    __builtin_amdgcn_s_setprio(0);
    asm volatile("s_waitcnt vmcnt(4)" ::: "memory");
    BAR(); FENCE();

    // ---- ph2: quad (i 4..7, j 0..1); stage A(0-63),A(128-191) of t+1 ----
#pragma unroll
    for (int i = 0; i < 4; i++)
#pragma unroll
      for (int kk = 0; kk < 2; kk++) aq[i][kk] = rdA(cur, i + 4, kk);
#pragma unroll
    for (int j = 0; j < 2; j++)
#pragma unroll
      for (int kk = 0; kk < 2; kk++) bq[j][kk] = rdB(cur, j, kk);
    stage1<4>(Ag, Bg, smem, tid, rowstride, m0, n0, kn, nxt);
    stage1<6>(Ag, Bg, smem, tid, rowstride, m0, n0, kn, nxt);
    FENCE(); BAR();
    __builtin_amdgcn_s_setprio(1);
#pragma unroll
    for (int i = 0; i < 4; i++)
#pragma unroll
      for (int j = 0; j < 2; j++)
#pragma unroll
        for (int kk = 0; kk < 2; kk++)
          acc[i + 4][j] = MM(aq[i][kk], bq[j][kk], acc[i + 4][j]);
    __builtin_amdgcn_s_setprio(0);
    FENCE(); BAR();

    // ---- ph3: quad (i 4..7, j 2..3); stage A(64-127),A(192-255);
    //      end-of-phase vmcnt(2): B-all + early-A of t+1 landed ----
#pragma unroll
    for (int j = 0; j < 2; j++)
#pragma unroll
      for (int kk = 0; kk < 2; kk++) bq[j][kk] = rdB(cur, j + 2, kk);
    stage1<5>(Ag, Bg, smem, tid, rowstride, m0, n0, kn, nxt);
    stage1<7>(Ag, Bg, smem, tid, rowstride, m0, n0, kn, nxt);
    FENCE(); BAR();
    __builtin_amdgcn_s_setprio(1);
#pragma unroll
    for (int i = 0; i < 4; i++)
#pragma unroll
      for (int j = 0; j < 2; j++)
#pragma unroll
        for (int kk = 0; kk < 2; kk++)
          acc[i + 4][j + 2] = MM(aq[i][kk], bq[j][kk], acc[i + 4][j + 2]);
    __builtin_amdgcn_s_setprio(0);
    asm volatile("s_waitcnt vmcnt(2)" ::: "memory");
    BAR(); FENCE();

    cur = nxt;
  }

  // ---- epilogue: frag C/D layout col=lane&15, row=(lane>>4)*4+r (m89) ----
  if constexpr (TRI) {
    const int R128 = (bm << 1) + (wid >> 2);
    const int C128 = (bn << 1) + ((wid & 3) >> 1);
    if (R128 > C128) return;                 // lower quad of diagonal tile
    const int t128 = R128 * 16 - (R128 * (R128 - 1)) / 2 + (C128 - R128);
    const int coff = ((wid & 1) << 6);
    float* base = Cmy + ((size_t)t128 << 14);
#pragma unroll
    for (int i = 0; i < 8; i++)
#pragma unroll
      for (int j = 0; j < 4; j++)
#pragma unroll
        for (int r = 0; r < 4; r++) {
          const int rl = (i << 4) + ((lane >> 4) << 2) + r;
          const int cl = coff + (j << 4) + (lane & 15);
          base[(rl << 7) + cl] = acc[i][j][r] * scale;
        }
  } else {
    const int wm = m0 + ((wid >> 2) << 7);
    const int wn = n0 + ((wid & 3) << 6);
#pragma unroll
    for (int i = 0; i < 8; i++)
#pragma unroll
      for (int j = 0; j < 4; j++)
#pragma unroll
        for (int r = 0; r < 4; r++) {
          const int rr = wm + (i << 4) + ((lane >> 4) << 2) + r;
          const int cc = wn + (j << 4) + (lane & 15);
          Cmy[(size_t)rr * (size_t)N + cc] = acc[i][j][r] * scale;
        }
  }
}

// ---------------------------------------------------------------------------
// reduce_sym: per upper-tri 128-tile b (grid=136), sum 4 compact fp32 partial
// planes -> bf16; write upper tile coalesced; write mirror tile (bm!=bn)
// via LDS transpose with coalesced row-runs. (proven in r4)
// ---------------------------------------------------------------------------
__global__ __launch_bounds__(256, 2)
void reduce_sym(const float* __restrict__ P, unsigned short* __restrict__ o)
{
  __shared__ unsigned short tl[128][136];
  const int b = (int)blockIdx.x;
  int rem = b, i = 0;
  while (rem >= 16 - i) { rem -= 16 - i; ++i; }
  const int bm = i, bn = i + rem;
  const int t = threadIdx.x;
  const size_t PS = (size_t)136 << 14;
  const float* p = P + ((size_t)b << 14);

#pragma unroll
  for (int s = 0; s < 16; s++) {
    const int idx = (s << 10) + (t << 2);
    const int r = idx >> 7, c = idx & 127;
    f32x4 v = *(const f32x4*)(p + idx);
    v += *(const f32x4*)(p + PS + idx);
    v += *(const f32x4*)(p + 2 * PS + idx);
    v += *(const f32x4*)(p + 3 * PS + idx);
    s16x4 u;
#pragma unroll
    for (int e = 0; e < 4; e++) u[e] = (short)f2bf(v[e]);
    *(s16x4*)(o + (((size_t)(bm << 7) + r) << 11) + (bn << 7) + c) = u;
#pragma unroll
    for (int e = 0; e < 4; e++) tl[c + e][r] = (unsigned short)u[e];
  }
  __syncthreads();
  if (bm == bn) return;

#pragma unroll
  for (int pass = 0; pass < 4; pass++) {
    const int crw = (pass << 5) + (t >> 3);
    const int r0  = (t & 7) << 4;
    const s16x8 w0 = *(const s16x8*)(&tl[crw][r0]);
    const s16x8 w1 = *(const s16x8*)(&tl[crw][r0 + 8]);
    unsigned short* od = o + (((size_t)(bn << 7) + crw) << 11) + (bm << 7) + r0;
    *(s16x8*)(od)     = w0;
    *(s16x8*)(od + 8) = w1;
  }
}

// ---------------------------------------------------------------------------
// y[row][0..3] = sum_c C_bf16[row][c] * v[c][0..3]   (2048 rows, 4 vectors)
// ---------------------------------------------------------------------------
__global__ __launch_bounds__(256)
void matvec4(const unsigned short* __restrict__ Cm,
             const float* __restrict__ vin, float* __restrict__ vout)
{
  const int row  = ((int)blockIdx.x << 2) + ((int)threadIdx.x >> 6);
  const int lane = threadIdx.x & 63;
  const unsigned short* crow = Cm + ((size_t)row << 11) + (lane << 5);
  const float* vp = vin + (lane << 7);
  float s0 = 0.f, s1 = 0.f, s2 = 0.f, s3 = 0.f;
#pragma unroll
  for (int u = 0; u < 4; u++) {
    const s16x8 cv = *(const s16x8*)(crow + (u << 3));
#pragma unroll
    for (int e = 0; e < 8; e++) {
      const float w = bf2f((unsigned short)cv[e]);
      const f32x4 vv = *(const f32x4*)(vp + (((u << 3) + e) << 2));
      s0 += w * vv[0]; s1 += w * vv[1]; s2 += w * vv[2]; s3 += w * vv[3];
    }
  }
#pragma unroll
  for (int d = 32; d > 0; d >>= 1) {
    s0 += __shfl_down(s0, d);
    s1 += __shfl_down(s1, d);
    s2 += __shfl_down(s2, d);
    s3 += __shfl_down(s3, d);
  }
  if (lane == 0) {
    float* o = vout + ((size_t)row << 2);
    o[0] = s0; o[1] = s1; o[2] = s2; o[3] = s3;
  }
}

__global__ void init_v(float* __restrict__ v) {
  const int i = (int)blockIdx.x * 256 + (int)threadIdx.x;  // 8192 values
  unsigned h = (unsigned)i * 2654435761u;
  h ^= h >> 16; h *= 2246822519u; h ^= h >> 13;
  v[i] = (float)(h & 0xFFFFFFu) * (2.0f / 16777216.0f) - 1.0f;
}

// R_j = (vt_j . y_j)/(vt_j . vt_j); sigma = 2*max_j R_j^(1/32); sig[0]=1/sigma
__global__ __launch_bounds__(256)
void rayleigh_k(const float* __restrict__ vt, const float* __restrict__ y,
                float* __restrict__ sig)
{
  __shared__ float part[4][8];
  const int t = threadIdx.x, lane = t & 63, w = t >> 6;
  float num[4] = {0, 0, 0, 0}, den[4] = {0, 0, 0, 0};
  for (int i = t; i < 2048; i += 256) {
    const f32x4 a = *(const f32x4*)(vt + ((size_t)i << 2));
    const f32x4 b = *(const f32x4*)(y + ((size_t)i << 2));
#pragma unroll
    for (int j = 0; j < 4; j++) { num[j] += a[j] * b[j]; den[j] += a[j] * a[j]; }
  }
#pragma unroll
  for (int d = 32; d > 0; d >>= 1)
#pragma unroll
    for (int j = 0; j < 4; j++) {
      num[j] += __shfl_down(num[j], d);
      den[j] += __shfl_down(den[j], d);
    }
  if (lane == 0) {
#pragma unroll
    for (int j = 0; j < 4; j++) { part[w][j] = num[j]; part[w][j + 4] = den[j]; }
  }
  __syncthreads();
  if (t == 0) {
    float R = 0.f;
#pragma unroll
    for (int j = 0; j < 4; j++) {
      const float nj = part[0][j] + part[1][j] + part[2][j] + part[3][j];
      const float dj = part[0][j + 4] + part[1][j + 4] + part[2][j + 4] + part[3][j + 4];
      R = fmaxf(R, nj / dj);
    }
    const float sigma = 2.0f * powf(R, 0.03125f);   // R^(1/32)
    sig[0] = 1.0f / sigma;
  }
}

__global__ __launch_bounds__(256)
void convert_f16(const float* __restrict__ in, _Float16* __restrict__ out) {
  const size_t i = (((size_t)blockIdx.x * 256) + threadIdx.x) << 3;
  const f32x4 a = *(const f32x4*)(in + i);
  const f32x4 b = *(const f32x4*)(in + i + 4);
  f16x8 o;
#pragma unroll
  for (int e = 0; e < 4; e++) { o[e] = (_Float16)a[e]; o[e + 4] = (_Float16)b[e]; }
  *(f16x8*)(out + i) = o;
}

// KT[f][d] = (f16) K[d][f], 64x64 tiles via LDS (stride 65: conflict-free)
__global__ __launch_bounds__(256)
void transpose_f16(const float* __restrict__ Kin, _Float16* __restrict__ KT) {
  __shared__ float tile[64][65];
  const int t = threadIdx.x;
  const int c = t & 63, rq = t >> 6;
  const int d0 = (int)blockIdx.x << 6, f0 = (int)blockIdx.y << 6;
#pragma unroll
  for (int p = 0; p < 16; p++) {
    const int rr = (p << 2) + rq;
    tile[rr][c] = Kin[(size_t)(d0 + rr) * 2048 + f0 + c];
  }
  __syncthreads();
#pragma unroll
  for (int p = 0; p < 16; p++) {
    const int fl = (p << 2) + rq;
    KT[(size_t)(f0 + fl) * 2048 + d0 + c] = (_Float16)tile[c][fl];
  }
}

// ---------------------------------------------------------------------------
extern "C" void kernel_launch(void* const* d_in, const int* in_sizes, int n_in,
                              void* d_out, int out_size, void* d_ws, size_t ws_size,
                              hipStream_t stream)
{
  (void)in_sizes; (void)n_in; (void)out_size; (void)ws_size;
  const float* X  = (const float*)d_in[0];   // [8192][2048] fp32
  const float* Km = (const float*)d_in[1];   // [2048][2048] fp32
  float* out = (float*)d_out;                // [8192][2048] fp32
  char* ws = (char*)d_ws;

  // Workspace (58 MiB live; X16 aliases P after the chain):
  _Float16* KT  = (_Float16*)ws;                              // [0,8M)
  unsigned short* buf0 = (unsigned short*)(ws + (8u << 20));  // [8M,16M)
  unsigned short* buf1 = (unsigned short*)(ws + (16u << 20)); // [16M,24M)
  float* P   = (float*)(ws + (24u << 20));                    // 4 compact planes, 34M
  _Float16* X16 = (_Float16*)(ws + (24u << 20));              // [24M,56M): reuses P
  float* V0  = (float*)(ws + (58u << 20));
  float* V1  = V0 + 8192;
  float* sig = V1 + 8192;

  transpose_f16<<<dim3(32, 32), 256, 0, stream>>>(Km, KT);

  // A~ = (K^T K)/4 : 36 upper 256-tiles, split-K=4, compact 128-tile partials
  gemm256<true, true><<<dim3(36, 4), 512, 0, stream>>>(
      (const char*)KT, (const char*)KT, P, 2048, 2048, 2048, 512, 0.25f, nullptr);
  reduce_sym<<<136, 256, 0, stream>>>(P, buf0);

  // 4 squarings: A~^2, A~^4, A~^8, A~^16 (all symmetric)
  unsigned short* src = buf0;
  unsigned short* dst = buf1;
  for (int s = 0; s < 4; s++) {
    gemm256<false, true><<<dim3(36, 4), 512, 0, stream>>>(
        (const char*)src, (const char*)src, P, 2048, 2048, 2048, 512, 1.0f, nullptr);
    reduce_sym<<<136, 256, 0, stream>>>(P, dst);
    unsigned short* t = src; src = dst; dst = t;
  }
  // C = A~^16 now in `src` (buf0)

  // X -> f16 (X16 aliases the dead P planes)
  convert_f16<<<8192, 256, 0, stream>>>(X, X16);

  // power iteration on C, 4 vectors, 5 multiplies
  init_v<<<32, 256, 0, stream>>>(V0);
  const int T = 5;
  for (int it = 0; it < T; it++)
    matvec4<<<512, 256, 0, stream>>>(src, (it & 1) ? V1 : V0, (it & 1) ? V0 : V1);
  const float* vt = ((T - 1) & 1) ? V1 : V0;
  const float* yv = ((T - 1) & 1) ? V0 : V1;
  rayleigh_k<<<1, 256, 0, stream>>>(vt, yv, sig);

  // out = X @ K / sigma : 32x8 = 256 blocks, 1/CU
  gemm256<true, false><<<dim3(256, 1), 512, 0, stream>>>(
      (const char*)X16, (const char*)KT, out, 8192, 2048, 2048, 2048, 1.0f, sig);
}

// Round 7
// 376.485 us; speedup vs baseline: 1.3951x; 1.0410x over previous
//
#include <hip/hip_runtime.h>
#include <hip/hip_bf16.h>

// SpectralDense on MI355X.
// out[8192][2048] = (X[8192][2048] @ K[2048][2048]) / sigma1(K)
// sigma1: A~ = K^T K / 4 -> 4 squarings -> C = A~^16 -> 4 power-iteration
// matvecs (4 vectors) -> Rayleigh -> sigma = 2 * R^(1/32).
//
// gemm256: 256^2 tile, BK=64, 512 thr / 8 waves (2Mx4N), 128 KiB LDS dbuf,
// counted-vmcnt schedule with TWO barriers per K-tile (r7):
//   {ph0,ph1: reads+MFMA+stage B0..B3(t+1)} -> vmcnt(4)+BAR ->
//   {ph2,ph3: reads+MFMA+stage A4,A6,A5,A7(t+1)} -> vmcnt(2)+BAR.
// Wave (wm,wn) reads B pass wn in EVERY phase-pair and A passes {wm? 6:4}
// early / {wm? 7:5} late. Queue proof: mid-tile outstanding =
// [A5(t),A7(t),B0-3(t+1)]=6 -> vmcnt(4) drains A-late(cur) (ph2/3 reads);
// tile-end outstanding = 8 of t+1 -> vmcnt(2) drains B-all+A-early (ph0/1
// reads of t+1). Intra-tile barriers removed: staging writes buf nxt only,
// reads touch buf cur only, so phase barriers separated disjoint buffers
// (r6 lock-stepped 8 waves for nothing -> MfmaUtil 37%).
// Never vmcnt(0) in-loop. LDS XOR swizzle byte^=((row&7)<<4) on BOTH global
// source (pre-swizzle for global_load_lds linear write) and ds_read (rule 21).
//
// Chain GEMMs: symmetric -> 36 upper-tri 256^2 tiles, split-K=4 (grid 36x4),
// quadrant epilogue into compact 136-tile fp32 partial planes; reduce_sym
// (proven r4) sums 4 planes, casts bf16, mirror-writes via LDS transpose.
// Workspace: 58 MiB live (X16 aliases dead partial planes).

typedef __attribute__((ext_vector_type(8))) _Float16 f16x8;
typedef __attribute__((ext_vector_type(8))) short   s16x8;
typedef __attribute__((ext_vector_type(4))) short   s16x4;
typedef __attribute__((ext_vector_type(4))) float   f32x4;

#define DEV __device__ __forceinline__
#define FENCE() asm volatile("" ::: "memory")
#define BAR()   __builtin_amdgcn_s_barrier()

DEV unsigned short f2bf(float x) {           // round-to-nearest-even fp32->bf16
  unsigned u = __float_as_uint(x);
  unsigned r = (u + 0x7FFFu + ((u >> 16) & 1u)) >> 16;
  return (unsigned short)r;
}
DEV float bf2f(unsigned short b) { return __uint_as_float(((unsigned)b) << 16); }

DEV void gl_lds16(const void* g, void* l) {
  __builtin_amdgcn_global_load_lds((const __attribute__((address_space(1))) void*)g,
                                   (__attribute__((address_space(3))) void*)l,
                                   16, 0, 0);
}

// one staging pass: 512 thr x 16 B = 8 KB. P<4: B rows P*64..+63; P>=4:
// A rows (P-4)*64..+63. LDS dest linear (global_load_lds requirement);
// global source column pre-swizzled so LDS lands XOR-swizzled.
template <int P>
DEV void stage1(const char* Ag, const char* Bg, unsigned char* smem,
                int tid, size_t rowstride, int m0, int n0, int kt, int buf)
{
  const int lb   = tid << 4;          // 0..8191
  const int rip  = lb >> 7;           // row in pass (0..63)
  const int colb = lb & 127;
  const int scb  = colb ^ ((rip & 7) << 4);
  if constexpr (P < 4) {
    const int grow = (P << 6) + rip;
    gl_lds16(Bg + (size_t)(n0 + grow) * rowstride + (size_t)kt * 2 + scb,
             smem + (buf << 16) + 32768 + (P << 13) + lb);
  } else {
    const int grow = ((P - 4) << 6) + rip;
    gl_lds16(Ag + (size_t)(m0 + grow) * rowstride + (size_t)kt * 2 + scb,
             smem + (buf << 16) + ((P - 4) << 13) + lb);
  }
}

// ---------------------------------------------------------------------------
// gemm256: C[m][n] = scale * sum_{k in split} A[m][k] * B[n][k]  (B^T layout)
// A: M x K, B: N x K (2-byte elems). 256^2 tile, BK=64, 512 threads.
// TRI: A==B symmetric, blockIdx.x in [0,36) upper-tri 256-tiles, quadrant
// epilogue into compact 136 x 128^2 fp32 planes (plane stride 136*16384).
// non-TRI: full row-major fp32 output with scale (and *scale_ptr if given).
// ---------------------------------------------------------------------------
template <bool F16IN, bool TRI>
__global__ __launch_bounds__(512, 2)
void gemm256(const char* __restrict__ Ag, const char* __restrict__ Bg,
             float* __restrict__ Cg, int M, int N, int K, int ksz,
             float cscale, const float* __restrict__ scale_ptr)
{
  __shared__ unsigned char smem[131072];    // 2 bufs x (A 32K + B 32K)
  const int tid  = threadIdx.x;
  const int lane = tid & 63;
  const int wid  = tid >> 6;                // 8 waves: wm=wid>>2, wn=wid&3

  int bm, bn;
  if constexpr (TRI) {
    int rem = (int)blockIdx.x, i = 0;       // upper-tri decode over 8x8
    while (rem >= 8 - i) { rem -= 8 - i; ++i; }
    bm = i; bn = i + rem;
  } else {
    const int q = (int)gridDim.x >> 3;      // XCD-bijective swizzle
    const int wgid = ((int)blockIdx.x & 7) * q + ((int)blockIdx.x >> 3);
    const int nbm = M >> 8;
    bm = wgid % nbm; bn = wgid / nbm;
  }
  const int m0 = bm << 8, n0 = bn << 8;

  const int kbeg = (int)blockIdx.y * ksz;
  const int NT   = ksz >> 6;
  float* __restrict__ Cmy =
      Cg + (size_t)blockIdx.y * (TRI ? ((size_t)136 << 14) : ((size_t)M * (size_t)N));

  float scale = cscale;
  if (scale_ptr) scale *= scale_ptr[0];

  const size_t rowstride = (size_t)K * 2;   // bytes

  const f32x4 zero = {0.f, 0.f, 0.f, 0.f};
  f32x4 acc[8][4];
#pragma unroll
  for (int i = 0; i < 8; i++)
#pragma unroll
    for (int j = 0; j < 4; j++) acc[i][j] = zero;

  // frag readers (both-sides swizzle)
  auto rdA = [&](int cur, int i, int kk) -> s16x8 {
    const int row = ((wid >> 2) << 7) + (i << 4) + (lane & 15);
    const int kb  = (kk << 6) + ((lane >> 4) << 4);
    return *(const s16x8*)(smem + (cur << 16) + (row << 7) + (kb ^ ((row & 7) << 4)));
  };
  auto rdB = [&](int cur, int j, int kk) -> s16x8 {
    const int row = ((wid & 3) << 6) + (j << 4) + (lane & 15);
    const int kb  = (kk << 6) + ((lane >> 4) << 4);
    return *(const s16x8*)(smem + (cur << 16) + 32768 + (row << 7) + (kb ^ ((row & 7) << 4)));
  };
  auto MM = [&](const s16x8& a, const s16x8& b, f32x4 c) -> f32x4 {
    if constexpr (F16IN)
      return __builtin_amdgcn_mfma_f32_16x16x32_f16(
          __builtin_bit_cast(f16x8, a), __builtin_bit_cast(f16x8, b), c, 0, 0, 0);
    else
      return __builtin_amdgcn_mfma_f32_16x16x32_bf16(a, b, c, 0, 0, 0);
  };

  // ---- prologue: stage tile 0, issue order B0..B3, A4, A6 (early), A5, A7
  //      (late); vmcnt(2) = oldest-6 landed (everything ph0/ph1 read) ----
  stage1<0>(Ag, Bg, smem, tid, rowstride, m0, n0, kbeg, 0);
  stage1<1>(Ag, Bg, smem, tid, rowstride, m0, n0, kbeg, 0);
  stage1<2>(Ag, Bg, smem, tid, rowstride, m0, n0, kbeg, 0);
  stage1<3>(Ag, Bg, smem, tid, rowstride, m0, n0, kbeg, 0);
  stage1<4>(Ag, Bg, smem, tid, rowstride, m0, n0, kbeg, 0);
  stage1<6>(Ag, Bg, smem, tid, rowstride, m0, n0, kbeg, 0);
  stage1<5>(Ag, Bg, smem, tid, rowstride, m0, n0, kbeg, 0);
  stage1<7>(Ag, Bg, smem, tid, rowstride, m0, n0, kbeg, 0);
  asm volatile("s_waitcnt vmcnt(2)" ::: "memory");
  BAR(); FENCE();

  int cur = 0;
  for (int t = 0; t < NT; ++t) {
    const int nxt = cur ^ 1;
    const int kn  = (t + 1 < NT) ? kbeg + ((t + 1) << 6) : kbeg;  // clamp tail
    s16x8 aq[4][2], bq[2][2];

    // ---- ph0: quad (i 0..3, j 0..1); stage B0,B1 of t+1 ----
#pragma unroll
    for (int i = 0; i < 4; i++)
#pragma unroll
      for (int kk = 0; kk < 2; kk++) aq[i][kk] = rdA(cur, i, kk);
#pragma unroll
    for (int j = 0; j < 2; j++)
#pragma unroll
      for (int kk = 0; kk < 2; kk++) bq[j][kk] = rdB(cur, j, kk);
    stage1<0>(Ag, Bg, smem, tid, rowstride, m0, n0, kn, nxt);
    stage1<1>(Ag, Bg, smem, tid, rowstride, m0, n0, kn, nxt);
    __builtin_amdgcn_s_setprio(1);
#pragma unroll
    for (int i = 0; i < 4; i++)
#pragma unroll
      for (int j = 0; j < 2; j++)
#pragma unroll
        for (int kk = 0; kk < 2; kk++)
          acc[i][j] = MM(aq[i][kk], bq[j][kk], acc[i][j]);
    __builtin_amdgcn_s_setprio(0);

    // ---- ph1: quad (i 0..3, j 2..3) reuse aq; stage B2,B3 ----
#pragma unroll
    for (int j = 0; j < 2; j++)
#pragma unroll
      for (int kk = 0; kk < 2; kk++) bq[j][kk] = rdB(cur, j + 2, kk);
    stage1<2>(Ag, Bg, smem, tid, rowstride, m0, n0, kn, nxt);
    stage1<3>(Ag, Bg, smem, tid, rowstride, m0, n0, kn, nxt);
    __builtin_amdgcn_s_setprio(1);
#pragma unroll
    for (int i = 0; i < 4; i++)
#pragma unroll
      for (int j = 0; j < 2; j++)
#pragma unroll
        for (int kk = 0; kk < 2; kk++)
          acc[i][j + 2] = MM(aq[i][kk], bq[j][kk], acc[i][j + 2]);
    __builtin_amdgcn_s_setprio(0);

    // ---- mid-tile sync: A-late of cur landed (ph2/ph3 read it) ----
    FENCE();
    asm volatile("s_waitcnt vmcnt(4)" ::: "memory");
    BAR(); FENCE();

    // ---- ph2: quad (i 4..7, j 0..1); stage A4,A6 (early-A of t+1) ----
#pragma unroll
    for (int i = 0; i < 4; i++)
#pragma unroll
      for (int kk = 0; kk < 2; kk++) aq[i][kk] = rdA(cur, i + 4, kk);
#pragma unroll
    for (int j = 0; j < 2; j++)
#pragma unroll
      for (int kk = 0; kk < 2; kk++) bq[j][kk] = rdB(cur, j, kk);
    stage1<4>(Ag, Bg, smem, tid, rowstride, m0, n0, kn, nxt);
    stage1<6>(Ag, Bg, smem, tid, rowstride, m0, n0, kn, nxt);
    __builtin_amdgcn_s_setprio(1);
#pragma unroll
    for (int i = 0; i < 4; i++)
#pragma unroll
      for (int j = 0; j < 2; j++)
#pragma unroll
        for (int kk = 0; kk < 2; kk++)
          acc[i + 4][j] = MM(aq[i][kk], bq[j][kk], acc[i + 4][j]);
    __builtin_amdgcn_s_setprio(0);

    // ---- ph3: quad (i 4..7, j 2..3); stage A5,A7 (late-A of t+1) ----
#pragma unroll
    for (int j = 0; j < 2; j++)
#pragma unroll
      for (int kk = 0; kk < 2; kk++) bq[j][kk] = rdB(cur, j + 2, kk);
    stage1<5>(Ag, Bg, smem, tid, rowstride, m0, n0, kn, nxt);
    stage1<7>(Ag, Bg, smem, tid, rowstride, m0, n0, kn, nxt);
    __builtin_amdgcn_s_setprio(1);
#pragma unroll
    for (int i = 0; i < 4; i++)
#pragma unroll
      for (int j = 0; j < 2; j++)
#pragma unroll
        for (int kk = 0; kk < 2; kk++)
          acc[i + 4][j + 2] = MM(aq[i][kk], bq[j][kk], acc[i + 4][j + 2]);
    __builtin_amdgcn_s_setprio(0);

    // ---- tile-end sync: B-all + early-A of t+1 landed; buffer swap ----
    FENCE();
    asm volatile("s_waitcnt vmcnt(2)" ::: "memory");
    BAR(); FENCE();

    cur = nxt;
  }

  // ---- epilogue: frag C/D layout col=lane&15, row=(lane>>4)*4+r (m89) ----
  if constexpr (TRI) {
    const int R128 = (bm << 1) + (wid >> 2);
    const int C128 = (bn << 1) + ((wid & 3) >> 1);
    if (R128 > C128) return;                 // lower quad of diagonal tile
    const int t128 = R128 * 16 - (R128 * (R128 - 1)) / 2 + (C128 - R128);
    const int coff = ((wid & 1) << 6);
    float* base = Cmy + ((size_t)t128 << 14);
#pragma unroll
    for (int i = 0; i < 8; i++)
#pragma unroll
      for (int j = 0; j < 4; j++)
#pragma unroll
        for (int r = 0; r < 4; r++) {
          const int rl = (i << 4) + ((lane >> 4) << 2) + r;
          const int cl = coff + (j << 4) + (lane & 15);
          base[(rl << 7) + cl] = acc[i][j][r] * scale;
        }
  } else {
    const int wm = m0 + ((wid >> 2) << 7);
    const int wn = n0 + ((wid & 3) << 6);
#pragma unroll
    for (int i = 0; i < 8; i++)
#pragma unroll
      for (int j = 0; j < 4; j++)
#pragma unroll
        for (int r = 0; r < 4; r++) {
          const int rr = wm + (i << 4) + ((lane >> 4) << 2) + r;
          const int cc = wn + (j << 4) + (lane & 15);
          Cmy[(size_t)rr * (size_t)N + cc] = acc[i][j][r] * scale;
        }
  }
}

// ---------------------------------------------------------------------------
// reduce_sym: per upper-tri 128-tile b (grid=136), sum 4 compact fp32 partial
// planes -> bf16; write upper tile coalesced; write mirror tile (bm!=bn)
// via LDS transpose with coalesced row-runs. (proven r4)
// ---------------------------------------------------------------------------
__global__ __launch_bounds__(256, 2)
void reduce_sym(const float* __restrict__ P, unsigned short* __restrict__ o)
{
  __shared__ unsigned short tl[128][136];
  const int b = (int)blockIdx.x;
  int rem = b, i = 0;
  while (rem >= 16 - i) { rem -= 16 - i; ++i; }
  const int bm = i, bn = i + rem;
  const int t = threadIdx.x;
  const size_t PS = (size_t)136 << 14;
  const float* p = P + ((size_t)b << 14);

#pragma unroll
  for (int s = 0; s < 16; s++) {
    const int idx = (s << 10) + (t << 2);
    const int r = idx >> 7, c = idx & 127;
    f32x4 v = *(const f32x4*)(p + idx);
    v += *(const f32x4*)(p + PS + idx);
    v += *(const f32x4*)(p + 2 * PS + idx);
    v += *(const f32x4*)(p + 3 * PS + idx);
    s16x4 u;
#pragma unroll
    for (int e = 0; e < 4; e++) u[e] = (short)f2bf(v[e]);
    *(s16x4*)(o + (((size_t)(bm << 7) + r) << 11) + (bn << 7) + c) = u;
#pragma unroll
    for (int e = 0; e < 4; e++) tl[c + e][r] = (unsigned short)u[e];
  }
  __syncthreads();
  if (bm == bn) return;

#pragma unroll
  for (int pass = 0; pass < 4; pass++) {
    const int crw = (pass << 5) + (t >> 3);
    const int r0  = (t & 7) << 4;
    const s16x8 w0 = *(const s16x8*)(&tl[crw][r0]);
    const s16x8 w1 = *(const s16x8*)(&tl[crw][r0 + 8]);
    unsigned short* od = o + (((size_t)(bn << 7) + crw) << 11) + (bm << 7) + r0;
    *(s16x8*)(od)     = w0;
    *(s16x8*)(od + 8) = w1;
  }
}

// ---------------------------------------------------------------------------
// y[row][0..3] = sum_c C_bf16[row][c] * v[c][0..3]   (2048 rows, 4 vectors)
// ---------------------------------------------------------------------------
__global__ __launch_bounds__(256)
void matvec4(const unsigned short* __restrict__ Cm,
             const float* __restrict__ vin, float* __restrict__ vout)
{
  const int row  = ((int)blockIdx.x << 2) + ((int)threadIdx.x >> 6);
  const int lane = threadIdx.x & 63;
  const unsigned short* crow = Cm + ((size_t)row << 11) + (lane << 5);
  const float* vp = vin + (lane << 7);
  float s0 = 0.f, s1 = 0.f, s2 = 0.f, s3 = 0.f;
#pragma unroll
  for (int u = 0; u < 4; u++) {
    const s16x8 cv = *(const s16x8*)(crow + (u << 3));
#pragma unroll
    for (int e = 0; e < 8; e++) {
      const float w = bf2f((unsigned short)cv[e]);
      const f32x4 vv = *(const f32x4*)(vp + (((u << 3) + e) << 2));
      s0 += w * vv[0]; s1 += w * vv[1]; s2 += w * vv[2]; s3 += w * vv[3];
    }
  }
#pragma unroll
  for (int d = 32; d > 0; d >>= 1) {
    s0 += __shfl_down(s0, d);
    s1 += __shfl_down(s1, d);
    s2 += __shfl_down(s2, d);
    s3 += __shfl_down(s3, d);
  }
  if (lane == 0) {
    float* o = vout + ((size_t)row << 2);
    o[0] = s0; o[1] = s1; o[2] = s2; o[3] = s3;
  }
}

__global__ void init_v(float* __restrict__ v) {
  const int i = (int)blockIdx.x * 256 + (int)threadIdx.x;  // 8192 values
  unsigned h = (unsigned)i * 2654435761u;
  h ^= h >> 16; h *= 2246822519u; h ^= h >> 13;
  v[i] = (float)(h & 0xFFFFFFu) * (2.0f / 16777216.0f) - 1.0f;
}

// R_j = (vt_j . y_j)/(vt_j . vt_j); sigma = 2*max_j R_j^(1/32); sig[0]=1/sigma
__global__ __launch_bounds__(256)
void rayleigh_k(const float* __restrict__ vt, const float* __restrict__ y,
                float* __restrict__ sig)
{
  __shared__ float part[4][8];
  const int t = threadIdx.x, lane = t & 63, w = t >> 6;
  float num[4] = {0, 0, 0, 0}, den[4] = {0, 0, 0, 0};
  for (int i = t; i < 2048; i += 256) {
    const f32x4 a = *(const f32x4*)(vt + ((size_t)i << 2));
    const f32x4 b = *(const f32x4*)(y + ((size_t)i << 2));
#pragma unroll
    for (int j = 0; j < 4; j++) { num[j] += a[j] * b[j]; den[j] += a[j] * a[j]; }
  }
#pragma unroll
  for (int d = 32; d > 0; d >>= 1)
#pragma unroll
    for (int j = 0; j < 4; j++) {
      num[j] += __shfl_down(num[j], d);
      den[j] += __shfl_down(den[j], d);
    }
  if (lane == 0) {
#pragma unroll
    for (int j = 0; j < 4; j++) { part[w][j] = num[j]; part[w][j + 4] = den[j]; }
  }
  __syncthreads();
  if (t == 0) {
    float R = 0.f;
#pragma unroll
    for (int j = 0; j < 4; j++) {
      const float nj = part[0][j] + part[1][j] + part[2][j] + part[3][j];
      const float dj = part[0][j + 4] + part[1][j + 4] + part[2][j + 4] + part[3][j + 4];
      R = fmaxf(R, nj / dj);
    }
    const float sigma = 2.0f * powf(R, 0.03125f);   // R^(1/32)
    sig[0] = 1.0f / sigma;
  }
}

__global__ __launch_bounds__(256)
void convert_f16(const float* __restrict__ in, _Float16* __restrict__ out) {
  const size_t i = (((size_t)blockIdx.x * 256) + threadIdx.x) << 3;
  const f32x4 a = *(const f32x4*)(in + i);
  const f32x4 b = *(const f32x4*)(in + i + 4);
  f16x8 o;
#pragma unroll
  for (int e = 0; e < 4; e++) { o[e] = (_Float16)a[e]; o[e + 4] = (_Float16)b[e]; }
  *(f16x8*)(out + i) = o;
}

// KT[f][d] = (f16) K[d][f], 64x64 tiles via LDS (stride 65: conflict-free)
__global__ __launch_bounds__(256)
void transpose_f16(const float* __restrict__ Kin, _Float16* __restrict__ KT) {
  __shared__ float tile[64][65];
  const int t = threadIdx.x;
  const int c = t & 63, rq = t >> 6;
  const int d0 = (int)blockIdx.x << 6, f0 = (int)blockIdx.y << 6;
#pragma unroll
  for (int p = 0; p < 16; p++) {
    const int rr = (p << 2) + rq;
    tile[rr][c] = Kin[(size_t)(d0 + rr) * 2048 + f0 + c];
  }
  __syncthreads();
#pragma unroll
  for (int p = 0; p < 16; p++) {
    const int fl = (p << 2) + rq;
    KT[(size_t)(f0 + fl) * 2048 + d0 + c] = (_Float16)tile[c][fl];
  }
}

// ---------------------------------------------------------------------------
extern "C" void kernel_launch(void* const* d_in, const int* in_sizes, int n_in,
                              void* d_out, int out_size, void* d_ws, size_t ws_size,
                              hipStream_t stream)
{
  (void)in_sizes; (void)n_in; (void)out_size; (void)ws_size;
  const float* X  = (const float*)d_in[0];   // [8192][2048] fp32
  const float* Km = (const float*)d_in[1];   // [2048][2048] fp32
  float* out = (float*)d_out;                // [8192][2048] fp32
  char* ws = (char*)d_ws;

  // Workspace (58 MiB live; X16 aliases P after the chain):
  _Float16* KT  = (_Float16*)ws;                              // [0,8M)
  unsigned short* buf0 = (unsigned short*)(ws + (8u << 20));  // [8M,16M)
  unsigned short* buf1 = (unsigned short*)(ws + (16u << 20)); // [16M,24M)
  float* P   = (float*)(ws + (24u << 20));                    // 4 compact planes, 34M
  _Float16* X16 = (_Float16*)(ws + (24u << 20));              // [24M,56M): reuses P
  float* V0  = (float*)(ws + (58u << 20));
  float* V1  = V0 + 8192;
  float* sig = V1 + 8192;

  transpose_f16<<<dim3(32, 32), 256, 0, stream>>>(Km, KT);

  // A~ = (K^T K)/4 : 36 upper 256-tiles, split-K=4, compact 128-tile partials
  gemm256<true, true><<<dim3(36, 4), 512, 0, stream>>>(
      (const char*)KT, (const char*)KT, P, 2048, 2048, 2048, 512, 0.25f, nullptr);
  reduce_sym<<<136, 256, 0, stream>>>(P, buf0);

  // 4 squarings: A~^2, A~^4, A~^8, A~^16 (all symmetric)
  unsigned short* src = buf0;
  unsigned short* dst = buf1;
  for (int s = 0; s < 4; s++) {
    gemm256<false, true><<<dim3(36, 4), 512, 0, stream>>>(
        (const char*)src, (const char*)src, P, 2048, 2048, 2048, 512, 1.0f, nullptr);
    reduce_sym<<<136, 256, 0, stream>>>(P, dst);
    unsigned short* t = src; src = dst; dst = t;
  }
  // C = A~^16 now in `src` (buf0)

  // X -> f16 (X16 aliases the dead P planes)
  convert_f16<<<8192, 256, 0, stream>>>(X, X16);

  // power iteration on C, 4 vectors, 4 multiplies
  init_v<<<32, 256, 0, stream>>>(V0);
  const int T = 4;
  for (int it = 0; it < T; it++)
    matvec4<<<512, 256, 0, stream>>>(src, (it & 1) ? V1 : V0, (it & 1) ? V0 : V1);
  const float* vt = ((T - 1) & 1) ? V1 : V0;   // input of last multiply
  const float* yv = ((T - 1) & 1) ? V0 : V1;   // output of last multiply
  rayleigh_k<<<1, 256, 0, stream>>>(vt, yv, sig);

  // out = X @ K / sigma : 32x8 = 256 blocks, 1/CU
  gemm256<true, false><<<dim3(256, 1), 512, 0, stream>>>(
      (const char*)X16, (const char*)KT, out, 8192, 2048, 2048, 2048, 1.0f, sig);
}